// Round 12
// baseline (560986.572 us; speedup 1.0000x reference)
//
#include <hip/hip_runtime.h>
#include <hip/hip_bf16.h>

// ---------------------------------------------------------------------------
// TernaryLSTM R26 = R20 (best, 10.67ms) with L2-FAST-PATH READS.
//   Insight: sc1 on a LOAD = bypass L2, read IC -> R20's poll iterations and
//   h-loads were forced IC round trips (~2-3us each) by construction. R22's
//   FETCH evidence proved groups (g=wg&7) are XCD-co-located: producer and
//   consumer share one L2. The producer's sc0sc1 STORE is a write-THROUGH
//   (updates local L2 + IC), so:
//   (1) consumer polls flags with sc0-only (bypass L1, read own L2): sees
//       the flag at L2 latency; if the store bypassed L2 the poll misses to
//       IC and still sees it. Budget escalation to sc0sc1 after 4096 tries
//       (formality) => worst case == R20.
//   (2) h-loads sc0-only: safe because wave4's vmcnt(0) ack puts h in
//       L2+IC BEFORE the flag exists; L2 hit or miss both read fresh data.
//   (3) wave4 dual flag store: sc0 first (local L2 asap), sc0sc1 second
//       (proven durable path).
//   STORES unchanged (sc0sc1 write-through, proven R15/R18/R19/R20). No
//   timers (R23/R25 refuted), no tags (R21/R24 refuted), no topology change.
//   Rest identical to R20: XCD groups g=wg&7, per-wave quarter waits,
//   flags 128B/line per (group,quarter), gates->LDS slab, wave4 blob
//   h-store + ack + flag off the gates path, Wr in VGPRs, Wk in LDS
//   (XOR-swizzled), xproj(t+1) in hidden window.
// ---------------------------------------------------------------------------

typedef __attribute__((ext_vector_type(8))) __bf16 bf16x8;
typedef __attribute__((ext_vector_type(4))) float f32x4;
typedef __attribute__((ext_vector_type(2))) unsigned int u32x2;

#define NWG 256
#define WGT 512
#define T_N 1024

// ---------------- alpha reductions -----------------------------------------
__global__ void absum_kernel(const float* __restrict__ w, int n,
                             double* __restrict__ partial) {
  __shared__ double sd[256];
  double s = 0.0;
  for (int i = blockIdx.x * 256 + threadIdx.x; i < n; i += 256 * 256)
    s += fabs((double)w[i]);
  sd[threadIdx.x] = s;
  __syncthreads();
  for (int k = 128; k > 0; k >>= 1) {
    if (threadIdx.x < k) sd[threadIdx.x] += sd[threadIdx.x + k];
    __syncthreads();
  }
  if (threadIdx.x == 0) partial[blockIdx.x] = sd[0];
}

__global__ void alpha_finalize(const double* __restrict__ pk,
                               const double* __restrict__ pr,
                               float* __restrict__ alphas) {
  __shared__ double sd[256];
  int t = threadIdx.x;
  sd[t] = pk[t];
  __syncthreads();
  for (int s = 128; s > 0; s >>= 1) {
    if (t < s) sd[t] += sd[t + s];
    __syncthreads();
  }
  if (t == 0) alphas[0] = (float)(sd[0] / (512.0 * 4096.0));
  __syncthreads();
  sd[t] = pr[t];
  __syncthreads();
  for (int s = 128; s > 0; s >>= 1) {
    if (t < s) sd[t] += sd[t + s];
    __syncthreads();
  }
  if (t == 0) alphas[1] = (float)(sd[0] / (1024.0 * 4096.0));
}

// ------ quantize + transpose to UNIT-MAJOR cols: wt[u*4+g][k] --------------
__global__ void quant_kernel(const float* __restrict__ w, int kbits,
                             const float* __restrict__ alphas, int ai,
                             __hip_bfloat16* __restrict__ wt, int total) {
  int idx = blockIdx.x * 256 + threadIdx.x;
  if (idx >= total) return;
  float thr = 0.7f * alphas[ai];
  int K = 1 << kbits;
  int c = idx >> kbits;  // unit-major col: unit = c>>2, gate = c&3
  int k = idx & (K - 1);
  float v = w[k * 4096 + (c & 3) * 1024 + (c >> 2)];
  float q = (fabsf(v) < thr) ? 0.0f : ((v > 0.0f) ? 1.0f : ((v < 0.0f) ? -1.0f : 0.0f));
  wt[idx] = __float2bfloat16(q);  // exact {-1,0,+1}
}

// ---------------- helpers ---------------------------------------------------
__device__ __forceinline__ bf16x8 cvt2(f32x4 a, f32x4 b) {
  bf16x8 r;
  r[0] = (__bf16)a[0]; r[1] = (__bf16)a[1];
  r[2] = (__bf16)a[2]; r[3] = (__bf16)a[3];
  r[4] = (__bf16)b[0]; r[5] = (__bf16)b[1];
  r[6] = (__bf16)b[2]; r[7] = (__bf16)b[3];
  return r;
}
// STORES: sc0 sc1 write-through (proven). READS: sc0-only = L2 fast path.
__device__ __forceinline__ void ld16l2(bf16x8* d, const __hip_bfloat16* p) {
  asm volatile("global_load_dwordx4 %0, %1, off sc0"
               : "=v"(*d) : "v"(p) : "memory");
}
__device__ __forceinline__ void st8cc(__hip_bfloat16* p, u32x2 v) {
  asm volatile("global_store_dwordx2 %0, %1, off sc0 sc1" ::"v"(p), "v"(v)
               : "memory");
}
__device__ __forceinline__ void stflag0(int* p, int v) {
  asm volatile("global_store_dword %0, %1, off sc0" ::"v"(p), "v"(v)
               : "memory");
}
__device__ __forceinline__ void stflag(int* p, int v) {
  asm volatile("global_store_dword %0, %1, off sc0 sc1" ::"v"(p), "v"(v)
               : "memory");
}
__device__ __forceinline__ int ldflag0(const int* p) {  // L2 fast-path poll
  int v;
  asm volatile("global_load_dword %0, %1, off sc0\n\ts_waitcnt vmcnt(0)"
               : "=v"(v) : "v"(p) : "memory");
  return v;
}
__device__ __forceinline__ int ldflag(const int* p) {  // proven IC poll
  int v;
  asm volatile("global_load_dword %0, %1, off sc0 sc1\n\ts_waitcnt vmcnt(0)"
               : "=v"(v) : "v"(p) : "memory");
  return v;
}
__device__ __forceinline__ unsigned bf16b(float f) {
  return (unsigned)__builtin_bit_cast(unsigned short, __float2bfloat16(f));
}
__device__ __forceinline__ float sigm(float z) { return 1.0f / (1.0f + __expf(-z)); }
__device__ __forceinline__ float tanhx(float z) {
  float e = __expf(-2.0f * fabsf(z));
  return __builtin_copysignf((1.0f - e) / (1.0f + e), z);
}

// ---------------- persistent LSTM kernel -----------------------------------
// flags layout: flags[(g*4 + quarter)*32 + slot], slot = u&7 (one 128B line
// per (group, quarter); 8 writers, 32 pollers per line).
__global__ void __launch_bounds__(WGT, 2)
lstm_persist(const float* __restrict__ bias4, const float* __restrict__ alphas,
             const float* __restrict__ x,             // [B][T][I] f32
             const __hip_bfloat16* __restrict__ wtk,  // [4096][512]  unit-major
             const __hip_bfloat16* __restrict__ wtr,  // [4096][1024] unit-major
             __hip_bfloat16* __restrict__ hbuf,       // [2][8][8][1024] bf16
             float* __restrict__ out,                 // [B][T][U] f32
             int* __restrict__ flags) {
  extern __shared__ char lds[];
  char* lwtk = lds;                     // 128 cols x 1024B swizzled = 131072
  float* lz = (float*)(lds + 131072);   // 4 slabs x [8][132] f32 = 16896
  float* lxz = (float*)(lds + 147968);  // 2 bufs  x [8][132] f32 = 8448
  unsigned short* lhs = (unsigned short*)(lds + 156416);  // 256 ushort = 512
  int* lmeta = (int*)(lds + 156928);    // [0..3] per-quarter epoch

  const int tid = threadIdx.x;
  const int wg = blockIdx.x;
  const int lane = tid & 63;
  const int wave = tid >> 6;
  const int r16 = lane & 15;
  const int kb8 = (lane >> 4) << 3;  // k-chunk 0,8,16,24

  const int g = wg & 7;    // XCD/IC-aligned software group (R22: FETCH 6x win)
  const int u = wg >> 3;   // unit-block 0..31: units [32u, 32u+32)
  const int rb0 = g << 3;  // group's first batch row

  if (tid < 4) lmeta[tid] = 0;

  // my flag slot (written by wave4 lane0): line (g, quarter u>>3), slot u&7
  int* myflag = flags + ((g << 2) + (u >> 3)) * 32 + (u & 7);
  // poll line for wave<4: quarter = wave
  const int* pollp = flags + ((g << 2) + (wave & 3)) * 32 + (lane & 7);

  // ---- stage Wk slice into LDS: local cols [0,128) = global [128u,+128) ---
  for (int it = tid; it < 8192; it += WGT) {
    int c = it >> 6, kk = (it & 63) << 3;
    bf16x8 v = *(const bf16x8*)(wtk + (size_t)(u * 128 + c) * 512 + kk);
    *(bf16x8*)(lwtk + (c << 10) + ((kk << 1) ^ ((c & 7) << 4))) = v;
  }

  // ---- Wr slice into VGPRs: wave w -> k-slice [(w&3)*256,+256),
  //      col half (w>>2)*64: 8 ksteps x 4 ntiles of bf16x8 frags ----
  const int ks0 = (wave & 3) << 8;
  bf16x8 bw[8][4];
  {
    const __hip_bfloat16* wb =
        wtr + (size_t)(u * 128 + ((wave >> 2) << 6) + r16) * 1024 + ks0 + kb8;
#pragma unroll
    for (int ks = 0; ks < 8; ++ks)
#pragma unroll
      for (int nt = 0; nt < 4; ++nt)
        bw[ks][nt] = *(const bf16x8*)(wb + (size_t)nt * 16 * 1024 + (ks << 5));
  }

  const float ak = alphas[0];
  const float ar = alphas[1];

  // gates mapping (threads 0..255): 1 cell = (row rl 0..7, unit-local ul 0..31)
  const int rl = tid >> 5;
  const int ul = tid & 31;
  float bias_c[4];
#pragma unroll
  for (int gg = 0; gg < 4; ++gg)
    bias_c[gg] = bias4[gg * 1024 + u * 32 + ul];
  float cst = 0.0f;
  float* outp = out + ((size_t)(rb0 + rl) << 20) + u * 32 + ul;

  // x-projection of step tt into lxz[par]: wave w does n-tile w (16 cols).
  auto xproj = [&](int tt, int par) {
    const float* xr =
        x + ((size_t)(rb0 + (r16 & 7)) << 19) + ((size_t)tt << 9) + kb8;
    const int cloc = (wave << 4) + r16;
    const char* bbase = lwtk + (cloc << 10);
    const int bxor = (cloc & 7) << 4;
    f32x4 a = {0.f, 0.f, 0.f, 0.f};
#pragma unroll
    for (int kw = 0; kw < 16; ++kw) {
      bf16x8 af = cvt2(*(const f32x4*)(xr + kw * 32),
                       *(const f32x4*)(xr + kw * 32 + 4));
      bf16x8 bf = *(const bf16x8*)(bbase + ((((kw << 5) + kb8) << 1) ^ bxor));
      a = __builtin_amdgcn_mfma_f32_16x16x32_bf16(af, bf, a, 0, 0, 0);
    }
    if (lane < 32) {
      float* dst = lxz + par * 1056 + (wave << 4) + (lane & 15);
#pragma unroll
      for (int j = 0; j < 4; ++j)
        dst[(((lane >> 4) << 2) + j) * 132] = a[j];
    }
  };

  __syncthreads();  // staging + lmeta visible
  xproj(0, 0);      // prologue: t=0 x-projection into lxz[0]

  // ---- main loop ----
  for (int t = 0; t < T_N; ++t) {
    // ---- rec: all 8 waves, per-wave producer wait + k-slice MFMA ----
    {
      f32x4 acc[4];
#pragma unroll
      for (int nt = 0; nt < 4; ++nt) acc[nt] = (f32x4){0.f, 0.f, 0.f, 0.f};
      if (t > 0) {
        // per-wave wait: quarter (w&3) needs its 8 producers at >= t.
        if (wave < 4) {
          int tries = 0;
          for (;;) {
            int v;
            if (lane < 8)
              v = (tries < 4096) ? ldflag0(pollp)   // L2 fast path
                                 : ldflag(pollp);   // proven IC path (escal.)
            else
              v = 0x7fffffff;
            if (__all(v >= t)) break;
            ++tries;
            __builtin_amdgcn_s_sleep(1);
          }
          if (lane == 0)
            __hip_atomic_store(&lmeta[wave], t, __ATOMIC_RELEASE,
                               __HIP_MEMORY_SCOPE_WORKGROUP);
        } else {
          while (__hip_atomic_load(&lmeta[wave - 4], __ATOMIC_ACQUIRE,
                                   __HIP_MEMORY_SCOPE_WORKGROUP) < t) {}
        }
        bf16x8 fr[8];
        if (r16 < 8) {  // A rows 8..15 are zero padding
          const __hip_bfloat16* hrow =
              hbuf + ((t & 1) << 16) + (g << 13) + (r16 << 10) + ks0 + kb8;
#pragma unroll
          for (int ks = 0; ks < 8; ++ks) ld16l2(&fr[ks], hrow + (ks << 5));
        } else {
#pragma unroll
          for (int ks = 0; ks < 8; ++ks)
#pragma unroll
            for (int j = 0; j < 8; ++j) fr[ks][j] = (__bf16)0.0f;
        }
        asm volatile("s_waitcnt vmcnt(0)" ::: "memory");
        __builtin_amdgcn_sched_barrier(0);
#pragma unroll
        for (int ks = 0; ks < 8; ++ks)
#pragma unroll
          for (int nt = 0; nt < 4; ++nt)
            acc[nt] = __builtin_amdgcn_mfma_f32_16x16x32_bf16(
                fr[ks], bw[ks][nt], acc[nt], 0, 0, 0);
      }
      if (lane < 32) {  // store C rows 0..7 only
        float* dst = lz + (wave & 3) * 1056 + ((wave >> 2) << 6) + (lane & 15);
#pragma unroll
        for (int nt = 0; nt < 4; ++nt)
#pragma unroll
          for (int j = 0; j < 4; ++j)
            dst[(((lane >> 4) << 2) + j) * 132 + (nt << 4)] = acc[nt][j];
      }
    }
    __syncthreads();  // sync1: lz partials + lxz[t&1] visible

    float ho = 0.0f;
    if (tid < 256) {  // ---- gates: 1 cell; h -> LDS slab (NO global ack) ----
      f32x4 z0 = *(const f32x4*)(lz + 0 * 1056 + rl * 132 + (ul << 2));
      f32x4 z1 = *(const f32x4*)(lz + 1 * 1056 + rl * 132 + (ul << 2));
      f32x4 z2 = *(const f32x4*)(lz + 2 * 1056 + rl * 132 + (ul << 2));
      f32x4 z3 = *(const f32x4*)(lz + 3 * 1056 + rl * 132 + (ul << 2));
      f32x4 z = z0 + z1 + z2 + z3;
      f32x4 xv = *(const f32x4*)(lxz + (t & 1) * 1056 + rl * 132 + (ul << 2));
      float zi = ak * xv[0] + bias_c[0] + ar * z[0];
      float zf = ak * xv[1] + bias_c[1] + ar * z[1];
      float zg = ak * xv[2] + bias_c[2] + ar * z[2];
      float zo = ak * xv[3] + bias_c[3] + ar * z[3];
      float ig = sigm(zi), fg = sigm(zf), gg = tanhx(zg), og = sigm(zo);
      float cn = fg * cst + ig * gg;
      cst = cn;
      ho = og * tanhx(cn);
      lhs[tid] = (unsigned short)bf16b(ho);
      outp[(size_t)t << 10] = ho;  // fire-and-forget cached store
    }
    __syncthreads();  // sync2: lhs visible to wave4

    // ---- wave4 alone: blob h-store + ack + dual flag (fast + durable) ----
    if (wave == 4) {
      u32x2 dv = *(const u32x2*)(lhs + (lane << 2));
      __hip_bfloat16* hb = hbuf + (((t + 1) & 1) << 16) + (g << 13) +
                           ((lane >> 3) << 10) + u * 32 + ((lane & 7) << 2);
      st8cc(hb, dv);
      asm volatile("s_waitcnt vmcnt(0)" ::: "memory");
      if (lane == 0) {
        stflag0(myflag, t + 1);  // local-L2 fast path
        stflag(myflag, t + 1);   // proven write-through path
      }
    }

    // ---- hidden window: x-projection of t+1 (all waves) ----
    if (t != T_N - 1) xproj(t + 1, (t + 1) & 1);
    // no end barrier: next iteration's per-wave wait is the sync
  }
}

// ---------------------------------------------------------------------------
extern "C" void kernel_launch(void* const* d_in, const int* in_sizes, int n_in,
                              void* d_out, int out_size, void* d_ws, size_t ws_size,
                              hipStream_t stream) {
  const float* x = (const float*)d_in[0];
  const float* wk = (const float*)d_in[1];
  const float* wr = (const float*)d_in[2];
  const float* bs = (const float*)d_in[3];
  float* out = (float*)d_out;
  char* ws = (char*)d_ws;

  float* alphas = (float*)(ws + 0);
  double* pk = (double*)(ws + 1024);   // 256 doubles: 1024..3072
  int* flags = (int*)(ws + 4096);      // 8 groups x 4 quarters x 128B = 4KB
  double* pr = (double*)(ws + 8192);   // 256 doubles: 8192..10240
  __hip_bfloat16* wtk = (__hip_bfloat16*)(ws + 16384);               // 4 MB
  __hip_bfloat16* wtr = (__hip_bfloat16*)(ws + 16384 + (4 << 20));   // 8 MB
  __hip_bfloat16* hbuf = (__hip_bfloat16*)(ws + 16384 + (12 << 20)); // 256 KB

  absum_kernel<<<256, 256, 0, stream>>>(wk, 512 * 4096, pk);
  absum_kernel<<<256, 256, 0, stream>>>(wr, 1024 * 4096, pr);
  alpha_finalize<<<1, 256, 0, stream>>>(pk, pr, alphas);
  quant_kernel<<<(4096 * 512) / 256, 256, 0, stream>>>(wk, 9, alphas, 0, wtk,
                                                       4096 * 512);
  quant_kernel<<<(4096 * 1024) / 256, 256, 0, stream>>>(wr, 10, alphas, 1, wtr,
                                                        4096 * 1024);
  (void)hipMemsetAsync(flags, 0, 4096);

  const int smem = 131072 + 16896 + 8448 + 512 + 64;  // 156992 B -> 1 WG/CU
  (void)hipFuncSetAttribute((const void*)lstm_persist,
                            hipFuncAttributeMaxDynamicSharedMemorySize, smem);
  void* args[] = {(void*)&bs,  (void*)&alphas, (void*)&x,   (void*)&wtk,
                  (void*)&wtr, (void*)&hbuf,   (void*)&out, (void*)&flags};
  (void)hipLaunchCooperativeKernel((void*)lstm_persist, dim3(NWG), dim3(WGT),
                                   args, smem, stream);
}

// Round 13
// 15970.891 us; speedup vs baseline: 35.1256x; 35.1256x over previous
//
#include <hip/hip_runtime.h>
#include <hip/hip_bf16.h>

// ---------------------------------------------------------------------------
// TernaryLSTM R27 = R24 (single-RT tagged h-exchange, refcheck-passing) with
// FIXED-PACE retries: s_sleep(1) -> s_sleep(16) (~1us quantum).
//   R24 counters showed its 16ms came from unpaced retry storms (VALUBusy
//   2x: each ~64-cycle-paced retry re-issues the 64KB group acquire and
//   delays the awaited stores). R25's EWMA pacing self-ratcheted (feedback
//   refuted). R26 proved sc0-only reads NEVER see sc0sc1 stores (stale L2,
//   561ms) -> everything stays sc0sc1.
//   Protocol (R21/R24-proven tags): producer (gates thread) stores f32
//   enc = h + (4*(t&3)+2), parity buffer (t+1)&1, fire-and-forget: NO ack,
//   NO flag, NO barrier after the store (any __syncthreads would drain
//   vmcnt and re-insert the ack RT). Consumer: speculative validated
//   acquire (16 sc0sc1 loads, 1 vmcnt, 64-value tag check), retry paced
//   s_sleep(16). Soundness: acquire(t+1) requires ALL 32 WGs' h(t) visible
//   (4 quarters cover the group), incl. own waves 0-3 whose stores issue
//   after their lz reads retire -> lz never overwritten under a reader;
//   lxz is parity-split; stale/mixed tags detected (centers differ by 8,
//   init-0 by 2, thr 1.002). Deadlock-free: producers store uncondition-
//   ally. Expected chain/step: ~1-2 IC RTs vs R20's 3.
//   Kept: XCD groups g=wg&7 (R22 FETCH 6x), Wr in VGPRs (8 waves x 32
//   bf16x8), Wk in LDS (128KB XOR-swizzled), gates 1 cell/thread,
//   xproj(t+1) in hidden window, single sync1/step.
// ---------------------------------------------------------------------------

typedef __attribute__((ext_vector_type(8))) __bf16 bf16x8;
typedef __attribute__((ext_vector_type(4))) float f32x4;

#define NWG 256
#define WGT 512
#define T_N 1024

// ---------------- alpha reductions -----------------------------------------
__global__ void absum_kernel(const float* __restrict__ w, int n,
                             double* __restrict__ partial) {
  __shared__ double sd[256];
  double s = 0.0;
  for (int i = blockIdx.x * 256 + threadIdx.x; i < n; i += 256 * 256)
    s += fabs((double)w[i]);
  sd[threadIdx.x] = s;
  __syncthreads();
  for (int k = 128; k > 0; k >>= 1) {
    if (threadIdx.x < k) sd[threadIdx.x] += sd[threadIdx.x + k];
    __syncthreads();
  }
  if (threadIdx.x == 0) partial[blockIdx.x] = sd[0];
}

__global__ void alpha_finalize(const double* __restrict__ pk,
                               const double* __restrict__ pr,
                               float* __restrict__ alphas) {
  __shared__ double sd[256];
  int t = threadIdx.x;
  sd[t] = pk[t];
  __syncthreads();
  for (int s = 128; s > 0; s >>= 1) {
    if (t < s) sd[t] += sd[t + s];
    __syncthreads();
  }
  if (t == 0) alphas[0] = (float)(sd[0] / (512.0 * 4096.0));
  __syncthreads();
  sd[t] = pr[t];
  __syncthreads();
  for (int s = 128; s > 0; s >>= 1) {
    if (t < s) sd[t] += sd[t + s];
    __syncthreads();
  }
  if (t == 0) alphas[1] = (float)(sd[0] / (1024.0 * 4096.0));
}

// ------ quantize + transpose to UNIT-MAJOR cols: wt[u*4+g][k] --------------
__global__ void quant_kernel(const float* __restrict__ w, int kbits,
                             const float* __restrict__ alphas, int ai,
                             __hip_bfloat16* __restrict__ wt, int total) {
  int idx = blockIdx.x * 256 + threadIdx.x;
  if (idx >= total) return;
  float thr = 0.7f * alphas[ai];
  int K = 1 << kbits;
  int c = idx >> kbits;  // unit-major col: unit = c>>2, gate = c&3
  int k = idx & (K - 1);
  float v = w[k * 4096 + (c & 3) * 1024 + (c >> 2)];
  float q = (fabsf(v) < thr) ? 0.0f : ((v > 0.0f) ? 1.0f : ((v < 0.0f) ? -1.0f : 0.0f));
  wt[idx] = __float2bfloat16(q);  // exact {-1,0,+1}
}

// ---------------- helpers ---------------------------------------------------
__device__ __forceinline__ bf16x8 cvt2(f32x4 a, f32x4 b) {
  bf16x8 r;
  r[0] = (__bf16)a[0]; r[1] = (__bf16)a[1];
  r[2] = (__bf16)a[2]; r[3] = (__bf16)a[3];
  r[4] = (__bf16)b[0]; r[5] = (__bf16)b[1];
  r[6] = (__bf16)b[2]; r[7] = (__bf16)b[3];
  return r;
}
// Device-scope (IC) exchange ops — sc0 sc1 (R26 proved sc0-only is unsafe).
__device__ __forceinline__ void ldf4cc(f32x4* d, const float* p) {
  asm volatile("global_load_dwordx4 %0, %1, off sc0 sc1"
               : "=v"(*d) : "v"(p) : "memory");
}
__device__ __forceinline__ void stfcc(float* p, float v) {
  asm volatile("global_store_dword %0, %1, off sc0 sc1" ::"v"(p), "v"(v)
               : "memory");
}
__device__ __forceinline__ float sigm(float z) { return 1.0f / (1.0f + __expf(-z)); }
__device__ __forceinline__ float tanhx(float z) {
  float e = __expf(-2.0f * fabsf(z));
  return __builtin_copysignf((1.0f - e) / (1.0f + e), z);
}

// ---------------- persistent LSTM kernel -----------------------------------
__global__ void __launch_bounds__(WGT, 2)
lstm_persist(const float* __restrict__ bias4, const float* __restrict__ alphas,
             const float* __restrict__ x,             // [B][T][I] f32
             const __hip_bfloat16* __restrict__ wtk,  // [4096][512]  unit-major
             const __hip_bfloat16* __restrict__ wtr,  // [4096][1024] unit-major
             float* __restrict__ henc,                // [2][8][8][1024] f32 enc
             float* __restrict__ out) {               // [B][T][U] f32
  extern __shared__ char lds[];
  char* lwtk = lds;                     // 128 cols x 1024B swizzled = 131072
  float* lz = (float*)(lds + 131072);   // 4 slabs x [8][132] f32 = 16896
  float* lxz = (float*)(lds + 147968);  // 2 bufs  x [8][132] f32 = 8448

  const int tid = threadIdx.x;
  const int wg = blockIdx.x;
  const int lane = tid & 63;
  const int wave = tid >> 6;
  const int r16 = lane & 15;
  const int kb8 = (lane >> 4) << 3;  // k-chunk 0,8,16,24

  const int g = wg & 7;    // XCD/IC-aligned software group (R22: FETCH 6x win)
  const int u = wg >> 3;   // unit-block 0..31: units [32u, 32u+32)
  const int rb0 = g << 3;  // group's first batch row

  // ---- stage Wk slice into LDS: local cols [0,128) = global [128u,+128) ---
  for (int it = tid; it < 8192; it += WGT) {
    int c = it >> 6, kk = (it & 63) << 3;
    bf16x8 v = *(const bf16x8*)(wtk + (size_t)(u * 128 + c) * 512 + kk);
    *(bf16x8*)(lwtk + (c << 10) + ((kk << 1) ^ ((c & 7) << 4))) = v;
  }

  // ---- Wr slice into VGPRs: wave w -> k-slice [(w&3)*256,+256),
  //      col half (w>>2)*64: 8 ksteps x 4 ntiles of bf16x8 frags ----
  const int ks0 = (wave & 3) << 8;
  bf16x8 bw[8][4];
  {
    const __hip_bfloat16* wb =
        wtr + (size_t)(u * 128 + ((wave >> 2) << 6) + r16) * 1024 + ks0 + kb8;
#pragma unroll
    for (int ks = 0; ks < 8; ++ks)
#pragma unroll
      for (int nt = 0; nt < 4; ++nt)
        bw[ks][nt] = *(const bf16x8*)(wb + (size_t)nt * 16 * 1024 + (ks << 5));
  }

  const float ak = alphas[0];
  const float ar = alphas[1];

  // gates mapping (threads 0..255): 1 cell = (row rl 0..7, unit-local ul 0..31)
  const int rl = tid >> 5;
  const int ul = tid & 31;
  float bias_c[4];
#pragma unroll
  for (int gg = 0; gg < 4; ++gg)
    bias_c[gg] = bias4[gg * 1024 + u * 32 + ul];
  float cst = 0.0f;
  float* hstf = henc + (((g << 3) + rl) << 10) + u * 32 + ul;  // + par<<16
  float* outp = out + ((size_t)(rb0 + rl) << 20) + u * 32 + ul;

  // consumer base (meaningful for r16<8; + par<<16)
  const float* hldb = henc + ((((g << 3) + (r16 & 7)) << 10)) + ks0 + kb8;

  // x-projection of step tt into lxz[par]: wave w does n-tile w (16 cols).
  auto xproj = [&](int tt, int par) {
    const float* xr =
        x + ((size_t)(rb0 + (r16 & 7)) << 19) + ((size_t)tt << 9) + kb8;
    const int cloc = (wave << 4) + r16;
    const char* bbase = lwtk + (cloc << 10);
    const int bxor = (cloc & 7) << 4;
    f32x4 a = {0.f, 0.f, 0.f, 0.f};
#pragma unroll
    for (int kw = 0; kw < 16; ++kw) {
      bf16x8 af = cvt2(*(const f32x4*)(xr + kw * 32),
                       *(const f32x4*)(xr + kw * 32 + 4));
      bf16x8 bf = *(const bf16x8*)(bbase + ((((kw << 5) + kb8) << 1) ^ bxor));
      a = __builtin_amdgcn_mfma_f32_16x16x32_bf16(af, bf, a, 0, 0, 0);
    }
    if (lane < 32) {
      float* dst = lxz + par * 1056 + (wave << 4) + (lane & 15);
#pragma unroll
      for (int j = 0; j < 4; ++j)
        dst[(((lane >> 4) << 2) + j) * 132] = a[j];
    }
  };

  __syncthreads();  // staging visible
  xproj(0, 0);      // prologue: t=0 x-projection into lxz[0]

  // ---- main loop ----
  for (int t = 0; t < T_N; ++t) {
    // ---- rec: all 8 waves, ONE speculative validated acquire + MFMA ----
    {
      f32x4 acc[4];
#pragma unroll
      for (int nt = 0; nt < 4; ++nt) acc[nt] = (f32x4){0.f, 0.f, 0.f, 0.f};
      if (t > 0) {
        const float cexp = (float)(4 * ((t - 1) & 3) + 2);  // expected center
        const float* hb = hldb + ((t & 1) << 16);
        f32x4 e[16];
        for (;;) {  // acquire: 16 loads, one vmcnt, validate all 64 values
          if (r16 < 8) {
#pragma unroll
            for (int ks = 0; ks < 8; ++ks) {
              ldf4cc(&e[2 * ks], hb + (ks << 5));
              ldf4cc(&e[2 * ks + 1], hb + (ks << 5) + 4);
            }
            asm volatile("s_waitcnt vmcnt(0)" ::: "memory");
          }
          float dev = 0.0f;
          if (r16 < 8) {
#pragma unroll
            for (int i = 0; i < 16; ++i)
#pragma unroll
              for (int j = 0; j < 4; ++j)
                dev = fmaxf(dev, fabsf(e[i][j] - cexp));
          }
          if (__all(dev < 1.002f)) break;
          __builtin_amdgcn_s_sleep(16);  // FIXED ~1us pacing (no feedback)
        }
        bf16x8 fr[8];
        if (r16 < 8) {
          const f32x4 c4 = {cexp, cexp, cexp, cexp};
#pragma unroll
          for (int ks = 0; ks < 8; ++ks)
            fr[ks] = cvt2(e[2 * ks] - c4, e[2 * ks + 1] - c4);
        } else {
#pragma unroll
          for (int ks = 0; ks < 8; ++ks)
#pragma unroll
            for (int j = 0; j < 8; ++j) fr[ks][j] = (__bf16)0.0f;
        }
        __builtin_amdgcn_sched_barrier(0);
#pragma unroll
        for (int ks = 0; ks < 8; ++ks)
#pragma unroll
          for (int nt = 0; nt < 4; ++nt)
            acc[nt] = __builtin_amdgcn_mfma_f32_16x16x32_bf16(
                fr[ks], bw[ks][nt], acc[nt], 0, 0, 0);
      }
      if (lane < 32) {  // store C rows 0..7 only
        float* dst = lz + (wave & 3) * 1056 + ((wave >> 2) << 6) + (lane & 15);
#pragma unroll
        for (int nt = 0; nt < 4; ++nt)
#pragma unroll
          for (int j = 0; j < 4; ++j)
            dst[(((lane >> 4) << 2) + j) * 132 + (nt << 4)] = acc[nt][j];
      }
    }
    __syncthreads();  // sync1: lz partials + lxz[t&1] visible

    if (tid < 256) {  // ---- gates: 1 cell; tagged f32 h, fire-and-forget ----
      f32x4 z0 = *(const f32x4*)(lz + 0 * 1056 + rl * 132 + (ul << 2));
      f32x4 z1 = *(const f32x4*)(lz + 1 * 1056 + rl * 132 + (ul << 2));
      f32x4 z2 = *(const f32x4*)(lz + 2 * 1056 + rl * 132 + (ul << 2));
      f32x4 z3 = *(const f32x4*)(lz + 3 * 1056 + rl * 132 + (ul << 2));
      f32x4 z = z0 + z1 + z2 + z3;
      f32x4 xv = *(const f32x4*)(lxz + (t & 1) * 1056 + rl * 132 + (ul << 2));
      float zi = ak * xv[0] + bias_c[0] + ar * z[0];
      float zf = ak * xv[1] + bias_c[1] + ar * z[1];
      float zg = ak * xv[2] + bias_c[2] + ar * z[2];
      float zo = ak * xv[3] + bias_c[3] + ar * z[3];
      float ig = sigm(zi), fg = sigm(zf), gg = tanhx(zg), og = sigm(zo);
      float cn = fg * cst + ig * gg;
      cst = cn;
      float ho = og * tanhx(cn);
      float cw = (float)(4 * (t & 3) + 2);  // write tag center for step t
      stfcc(hstf + (((t + 1) & 1) << 16), cw + ho);  // h FIRST (critical path)
      outp[(size_t)t << 10] = ho;                    // then cached out store
    }
    // NO sync2 (it would vmcnt-drain the h-store = re-insert the ack RT).
    // Safety: acquire(t+1) anywhere requires ALL 32 WGs' h(t) visible,
    // incl. own waves 0-3 whose stores issue after their lz reads retire
    // -> lz never overwritten under a reader; lxz is parity-split.

    // ---- hidden window: x-projection of t+1 (all waves) ----
    if (t != T_N - 1) xproj(t + 1, (t + 1) & 1);
  }
}

// ---------------------------------------------------------------------------
extern "C" void kernel_launch(void* const* d_in, const int* in_sizes, int n_in,
                              void* d_out, int out_size, void* d_ws, size_t ws_size,
                              hipStream_t stream) {
  const float* x = (const float*)d_in[0];
  const float* wk = (const float*)d_in[1];
  const float* wr = (const float*)d_in[2];
  const float* bs = (const float*)d_in[3];
  float* out = (float*)d_out;
  char* ws = (char*)d_ws;

  float* alphas = (float*)(ws + 0);
  double* pk = (double*)(ws + 1024);   // 256 doubles: 1024..3072
  double* pr = (double*)(ws + 8192);   // 256 doubles: 8192..10240
  __hip_bfloat16* wtk = (__hip_bfloat16*)(ws + 16384);               // 4 MB
  __hip_bfloat16* wtr = (__hip_bfloat16*)(ws + 16384 + (4 << 20));   // 8 MB
  float* henc = (float*)(ws + 16384 + (12 << 20));                   // 512 KB

  absum_kernel<<<256, 256, 0, stream>>>(wk, 512 * 4096, pk);
  absum_kernel<<<256, 256, 0, stream>>>(wr, 1024 * 4096, pr);
  alpha_finalize<<<1, 256, 0, stream>>>(pk, pr, alphas);
  quant_kernel<<<(4096 * 512) / 256, 256, 0, stream>>>(wk, 9, alphas, 0, wtk,
                                                       4096 * 512);
  quant_kernel<<<(4096 * 1024) / 256, 256, 0, stream>>>(wr, 10, alphas, 1, wtr,
                                                        4096 * 1024);
  (void)hipMemsetAsync(henc, 0, 2 * 8 * 8 * 1024 * 4);  // invalid tag (0)

  const int smem = 131072 + 16896 + 8448;  // 156416 B -> 1 WG/CU
  (void)hipFuncSetAttribute((const void*)lstm_persist,
                            hipFuncAttributeMaxDynamicSharedMemorySize, smem);
  void* args[] = {(void*)&bs,  (void*)&alphas, (void*)&x, (void*)&wtk,
                  (void*)&wtr, (void*)&henc,   (void*)&out};
  (void)hipLaunchCooperativeKernel((void*)lstm_persist, dim3(NWG), dim3(WGT),
                                   args, smem, stream);
}

// Round 14
// 10683.673 us; speedup vs baseline: 52.5088x; 1.4949x over previous
//
#include <hip/hip_runtime.h>
#include <hip/hip_bf16.h>

// ---------------------------------------------------------------------------
// TernaryLSTM R28 = EXACT REVERT to R20 (session best: 10.668 ms).
//   Final configuration after the full experiment ledger (R15-R27):
//   - software groups g=wg>>5 (beats XCD-aligned g=wg&7 by ~0.6ms despite
//     6x more HBM fetch — hot sync lines spread across IC slices);
//   - per-wave quarter waits: waves 0-3 poll 8 producer flags (one 128B
//     line per (group,quarter)), post LDS epoch; waves 4-7 take epoch;
//   - gates write h to a 512B LDS slab (no global ack on the 256-thread
//     path); wave4 alone blob-stores the slice (64x dwordx2 sc0sc1) +
//     vmcnt(0) + lane0 flag, overlapping the ack with other waves' xproj;
//   - poll backoff s_sleep(2);
//   - Wr in VGPRs (8 waves x 32 bf16x8, zero per-step weight traffic);
//     Wk in LDS (128KB XOR-swizzled); xproj(t+1) in the hidden window;
//   - ALL cross-WG ops sc0 sc1 (R26 proved sc0-only reads never observe
//     sc0sc1 stores).
//   Structural floor: 1024 sequential steps x (~3 dependent IC RTs
//   (~2.5us each under load) + ~2.5us compute) ~= 10.4us/step. Refuted
//   alternatives: topology variants (R18/19), locality (R22), contention
//   pacing (R23/25), L2 read path (R26), 1-RT tagged exchange (R21/24/27).
// ---------------------------------------------------------------------------

typedef __attribute__((ext_vector_type(8))) __bf16 bf16x8;
typedef __attribute__((ext_vector_type(4))) float f32x4;
typedef __attribute__((ext_vector_type(2))) unsigned int u32x2;

#define NWG 256
#define WGT 512
#define T_N 1024

// ---------------- alpha reductions -----------------------------------------
__global__ void absum_kernel(const float* __restrict__ w, int n,
                             double* __restrict__ partial) {
  __shared__ double sd[256];
  double s = 0.0;
  for (int i = blockIdx.x * 256 + threadIdx.x; i < n; i += 256 * 256)
    s += fabs((double)w[i]);
  sd[threadIdx.x] = s;
  __syncthreads();
  for (int k = 128; k > 0; k >>= 1) {
    if (threadIdx.x < k) sd[threadIdx.x] += sd[threadIdx.x + k];
    __syncthreads();
  }
  if (threadIdx.x == 0) partial[blockIdx.x] = sd[0];
}

__global__ void alpha_finalize(const double* __restrict__ pk,
                               const double* __restrict__ pr,
                               float* __restrict__ alphas) {
  __shared__ double sd[256];
  int t = threadIdx.x;
  sd[t] = pk[t];
  __syncthreads();
  for (int s = 128; s > 0; s >>= 1) {
    if (t < s) sd[t] += sd[t + s];
    __syncthreads();
  }
  if (t == 0) alphas[0] = (float)(sd[0] / (512.0 * 4096.0));
  __syncthreads();
  sd[t] = pr[t];
  __syncthreads();
  for (int s = 128; s > 0; s >>= 1) {
    if (t < s) sd[t] += sd[t + s];
    __syncthreads();
  }
  if (t == 0) alphas[1] = (float)(sd[0] / (1024.0 * 4096.0));
}

// ------ quantize + transpose to UNIT-MAJOR cols: wt[u*4+g][k] --------------
__global__ void quant_kernel(const float* __restrict__ w, int kbits,
                             const float* __restrict__ alphas, int ai,
                             __hip_bfloat16* __restrict__ wt, int total) {
  int idx = blockIdx.x * 256 + threadIdx.x;
  if (idx >= total) return;
  float thr = 0.7f * alphas[ai];
  int K = 1 << kbits;
  int c = idx >> kbits;  // unit-major col: unit = c>>2, gate = c&3
  int k = idx & (K - 1);
  float v = w[k * 4096 + (c & 3) * 1024 + (c >> 2)];
  float q = (fabsf(v) < thr) ? 0.0f : ((v > 0.0f) ? 1.0f : ((v < 0.0f) ? -1.0f : 0.0f));
  wt[idx] = __float2bfloat16(q);  // exact {-1,0,+1}
}

// ---------------- helpers ---------------------------------------------------
__device__ __forceinline__ bf16x8 cvt2(f32x4 a, f32x4 b) {
  bf16x8 r;
  r[0] = (__bf16)a[0]; r[1] = (__bf16)a[1];
  r[2] = (__bf16)a[2]; r[3] = (__bf16)a[3];
  r[4] = (__bf16)b[0]; r[5] = (__bf16)b[1];
  r[6] = (__bf16)b[2]; r[7] = (__bf16)b[3];
  return r;
}
// Device-scope (IC) ops — R12/R15/R18/R19/R20-proven protocol.
__device__ __forceinline__ void ld16cc(bf16x8* d, const __hip_bfloat16* p) {
  asm volatile("global_load_dwordx4 %0, %1, off sc0 sc1"
               : "=v"(*d) : "v"(p) : "memory");
}
__device__ __forceinline__ void st8cc(__hip_bfloat16* p, u32x2 v) {
  asm volatile("global_store_dwordx2 %0, %1, off sc0 sc1" ::"v"(p), "v"(v)
               : "memory");
}
__device__ __forceinline__ void stflag(int* p, int v) {
  asm volatile("global_store_dword %0, %1, off sc0 sc1" ::"v"(p), "v"(v)
               : "memory");
}
__device__ __forceinline__ int ldflag(const int* p) {
  int v;
  asm volatile("global_load_dword %0, %1, off sc0 sc1\n\ts_waitcnt vmcnt(0)"
               : "=v"(v) : "v"(p) : "memory");
  return v;
}
__device__ __forceinline__ unsigned bf16b(float f) {
  return (unsigned)__builtin_bit_cast(unsigned short, __float2bfloat16(f));
}
__device__ __forceinline__ float sigm(float z) { return 1.0f / (1.0f + __expf(-z)); }
__device__ __forceinline__ float tanhx(float z) {
  float e = __expf(-2.0f * fabsf(z));
  return __builtin_copysignf((1.0f - e) / (1.0f + e), z);
}

// ---------------- persistent LSTM kernel -----------------------------------
// flags layout: flags[(g*4 + quarter)*32 + slot], slot = u&7 (one 128B line
// per (group, quarter); 8 writers, 32 pollers per line).
__global__ void __launch_bounds__(WGT, 2)
lstm_persist(const float* __restrict__ bias4, const float* __restrict__ alphas,
             const float* __restrict__ x,             // [B][T][I] f32
             const __hip_bfloat16* __restrict__ wtk,  // [4096][512]  unit-major
             const __hip_bfloat16* __restrict__ wtr,  // [4096][1024] unit-major
             __hip_bfloat16* __restrict__ hbuf,       // [2][8][8][1024] bf16
             float* __restrict__ out,                 // [B][T][U] f32
             int* __restrict__ flags) {
  extern __shared__ char lds[];
  char* lwtk = lds;                     // 128 cols x 1024B swizzled = 131072
  float* lz = (float*)(lds + 131072);   // 4 slabs x [8][132] f32 = 16896
  float* lxz = (float*)(lds + 147968);  // 2 bufs  x [8][132] f32 = 8448
  unsigned short* lhs = (unsigned short*)(lds + 156416);  // 256 ushort = 512
  int* lmeta = (int*)(lds + 156928);    // [0..3] per-quarter epoch

  const int tid = threadIdx.x;
  const int wg = blockIdx.x;
  const int lane = tid & 63;
  const int wave = tid >> 6;
  const int r16 = lane & 15;
  const int kb8 = (lane >> 4) << 3;  // k-chunk 0,8,16,24

  const int g = wg >> 5;   // software group 0..7 (8 batch rows each)
  const int u = wg & 31;   // unit-block 0..31: units [32u, 32u+32)
  const int rb0 = g << 3;  // group's first batch row

  if (tid < 4) lmeta[tid] = 0;

  // my flag slot (written by wave4 lane0): line (g, quarter u>>3), slot u&7
  int* myflag = flags + ((g << 2) + (u >> 3)) * 32 + (u & 7);
  // poll line for wave<4: quarter = wave
  const int* pollp = flags + ((g << 2) + (wave & 3)) * 32 + (lane & 7);

  // ---- stage Wk slice into LDS: local cols [0,128) = global [128u,+128) ---
  for (int it = tid; it < 8192; it += WGT) {
    int c = it >> 6, kk = (it & 63) << 3;
    bf16x8 v = *(const bf16x8*)(wtk + (size_t)(u * 128 + c) * 512 + kk);
    *(bf16x8*)(lwtk + (c << 10) + ((kk << 1) ^ ((c & 7) << 4))) = v;
  }

  // ---- Wr slice into VGPRs: wave w -> k-slice [(w&3)*256,+256),
  //      col half (w>>2)*64: 8 ksteps x 4 ntiles of bf16x8 frags ----
  const int ks0 = (wave & 3) << 8;
  bf16x8 bw[8][4];
  {
    const __hip_bfloat16* wb =
        wtr + (size_t)(u * 128 + ((wave >> 2) << 6) + r16) * 1024 + ks0 + kb8;
#pragma unroll
    for (int ks = 0; ks < 8; ++ks)
#pragma unroll
      for (int nt = 0; nt < 4; ++nt)
        bw[ks][nt] = *(const bf16x8*)(wb + (size_t)nt * 16 * 1024 + (ks << 5));
  }

  const float ak = alphas[0];
  const float ar = alphas[1];

  // gates mapping (threads 0..255): 1 cell = (row rl 0..7, unit-local ul 0..31)
  const int rl = tid >> 5;
  const int ul = tid & 31;
  float bias_c[4];
#pragma unroll
  for (int gg = 0; gg < 4; ++gg)
    bias_c[gg] = bias4[gg * 1024 + u * 32 + ul];
  float cst = 0.0f;
  float* outp = out + ((size_t)(rb0 + rl) << 20) + u * 32 + ul;

  // x-projection of step tt into lxz[par]: wave w does n-tile w (16 cols).
  auto xproj = [&](int tt, int par) {
    const float* xr =
        x + ((size_t)(rb0 + (r16 & 7)) << 19) + ((size_t)tt << 9) + kb8;
    const int cloc = (wave << 4) + r16;
    const char* bbase = lwtk + (cloc << 10);
    const int bxor = (cloc & 7) << 4;
    f32x4 a = {0.f, 0.f, 0.f, 0.f};
#pragma unroll
    for (int kw = 0; kw < 16; ++kw) {
      bf16x8 af = cvt2(*(const f32x4*)(xr + kw * 32),
                       *(const f32x4*)(xr + kw * 32 + 4));
      bf16x8 bf = *(const bf16x8*)(bbase + ((((kw << 5) + kb8) << 1) ^ bxor));
      a = __builtin_amdgcn_mfma_f32_16x16x32_bf16(af, bf, a, 0, 0, 0);
    }
    if (lane < 32) {
      float* dst = lxz + par * 1056 + (wave << 4) + (lane & 15);
#pragma unroll
      for (int j = 0; j < 4; ++j)
        dst[(((lane >> 4) << 2) + j) * 132] = a[j];
    }
  };

  __syncthreads();  // staging + lmeta visible
  xproj(0, 0);      // prologue: t=0 x-projection into lxz[0]

  // ---- main loop ----
  for (int t = 0; t < T_N; ++t) {
    // ---- rec: all 8 waves, per-wave producer wait + k-slice MFMA ----
    {
      f32x4 acc[4];
#pragma unroll
      for (int nt = 0; nt < 4; ++nt) acc[nt] = (f32x4){0.f, 0.f, 0.f, 0.f};
      if (t > 0) {
        // per-wave wait: quarter (w&3) needs its 8 producers at >= t.
        if (wave < 4) {
          for (;;) {
            int v = (lane < 8) ? ldflag(pollp) : 0x7fffffff;
            if (__all(v >= t)) break;
            __builtin_amdgcn_s_sleep(2);  // backoff: cut IC poll pressure
          }
          if (lane == 0)
            __hip_atomic_store(&lmeta[wave], t, __ATOMIC_RELEASE,
                               __HIP_MEMORY_SCOPE_WORKGROUP);
        } else {
          while (__hip_atomic_load(&lmeta[wave - 4], __ATOMIC_ACQUIRE,
                                   __HIP_MEMORY_SCOPE_WORKGROUP) < t) {}
        }
        bf16x8 fr[8];
        if (r16 < 8) {  // A rows 8..15 are zero padding
          const __hip_bfloat16* hrow =
              hbuf + ((t & 1) << 16) + (g << 13) + (r16 << 10) + ks0 + kb8;
#pragma unroll
          for (int ks = 0; ks < 8; ++ks) ld16cc(&fr[ks], hrow + (ks << 5));
        } else {
#pragma unroll
          for (int ks = 0; ks < 8; ++ks)
#pragma unroll
            for (int j = 0; j < 8; ++j) fr[ks][j] = (__bf16)0.0f;
        }
        asm volatile("s_waitcnt vmcnt(0)" ::: "memory");
        __builtin_amdgcn_sched_barrier(0);
#pragma unroll
        for (int ks = 0; ks < 8; ++ks)
#pragma unroll
          for (int nt = 0; nt < 4; ++nt)
            acc[nt] = __builtin_amdgcn_mfma_f32_16x16x32_bf16(
                fr[ks], bw[ks][nt], acc[nt], 0, 0, 0);
      }
      if (lane < 32) {  // store C rows 0..7 only
        float* dst = lz + (wave & 3) * 1056 + ((wave >> 2) << 6) + (lane & 15);
#pragma unroll
        for (int nt = 0; nt < 4; ++nt)
#pragma unroll
          for (int j = 0; j < 4; ++j)
            dst[(((lane >> 4) << 2) + j) * 132 + (nt << 4)] = acc[nt][j];
      }
    }
    __syncthreads();  // sync1: lz partials + lxz[t&1] visible

    float ho = 0.0f;
    if (tid < 256) {  // ---- gates: 1 cell; h -> LDS slab (NO global ack) ----
      f32x4 z0 = *(const f32x4*)(lz + 0 * 1056 + rl * 132 + (ul << 2));
      f32x4 z1 = *(const f32x4*)(lz + 1 * 1056 + rl * 132 + (ul << 2));
      f32x4 z2 = *(const f32x4*)(lz + 2 * 1056 + rl * 132 + (ul << 2));
      f32x4 z3 = *(const f32x4*)(lz + 3 * 1056 + rl * 132 + (ul << 2));
      f32x4 z = z0 + z1 + z2 + z3;
      f32x4 xv = *(const f32x4*)(lxz + (t & 1) * 1056 + rl * 132 + (ul << 2));
      float zi = ak * xv[0] + bias_c[0] + ar * z[0];
      float zf = ak * xv[1] + bias_c[1] + ar * z[1];
      float zg = ak * xv[2] + bias_c[2] + ar * z[2];
      float zo = ak * xv[3] + bias_c[3] + ar * z[3];
      float ig = sigm(zi), fg = sigm(zf), gg = tanhx(zg), og = sigm(zo);
      float cn = fg * cst + ig * gg;
      cst = cn;
      ho = og * tanhx(cn);
      lhs[tid] = (unsigned short)bf16b(ho);
      outp[(size_t)t << 10] = ho;  // fire-and-forget cached store
    }
    __syncthreads();  // sync2: lhs visible to wave4

    // ---- wave4 alone: blob h-store + ack + flag (overlaps others' xproj) --
    if (wave == 4) {
      u32x2 dv = *(const u32x2*)(lhs + (lane << 2));
      __hip_bfloat16* hb = hbuf + (((t + 1) & 1) << 16) + (g << 13) +
                           ((lane >> 3) << 10) + u * 32 + ((lane & 7) << 2);
      st8cc(hb, dv);
      asm volatile("s_waitcnt vmcnt(0)" ::: "memory");
      if (lane == 0) stflag(myflag, t + 1);
    }

    // ---- hidden window: x-projection of t+1 (all waves) ----
    if (t != T_N - 1) xproj(t + 1, (t + 1) & 1);
    // no end barrier: next iteration's per-wave wait is the sync
  }
}

// ---------------------------------------------------------------------------
extern "C" void kernel_launch(void* const* d_in, const int* in_sizes, int n_in,
                              void* d_out, int out_size, void* d_ws, size_t ws_size,
                              hipStream_t stream) {
  const float* x = (const float*)d_in[0];
  const float* wk = (const float*)d_in[1];
  const float* wr = (const float*)d_in[2];
  const float* bs = (const float*)d_in[3];
  float* out = (float*)d_out;
  char* ws = (char*)d_ws;

  float* alphas = (float*)(ws + 0);
  double* pk = (double*)(ws + 1024);   // 256 doubles: 1024..3072
  int* flags = (int*)(ws + 4096);      // 8 groups x 4 quarters x 128B = 4KB
  double* pr = (double*)(ws + 8192);   // 256 doubles: 8192..10240
  __hip_bfloat16* wtk = (__hip_bfloat16*)(ws + 16384);               // 4 MB
  __hip_bfloat16* wtr = (__hip_bfloat16*)(ws + 16384 + (4 << 20));   // 8 MB
  __hip_bfloat16* hbuf = (__hip_bfloat16*)(ws + 16384 + (12 << 20)); // 256 KB

  absum_kernel<<<256, 256, 0, stream>>>(wk, 512 * 4096, pk);
  absum_kernel<<<256, 256, 0, stream>>>(wr, 1024 * 4096, pr);
  alpha_finalize<<<1, 256, 0, stream>>>(pk, pr, alphas);
  quant_kernel<<<(4096 * 512) / 256, 256, 0, stream>>>(wk, 9, alphas, 0, wtk,
                                                       4096 * 512);
  quant_kernel<<<(4096 * 1024) / 256, 256, 0, stream>>>(wr, 10, alphas, 1, wtr,
                                                        4096 * 1024);
  (void)hipMemsetAsync(flags, 0, 4096);

  const int smem = 131072 + 16896 + 8448 + 512 + 64;  // 156992 B -> 1 WG/CU
  (void)hipFuncSetAttribute((const void*)lstm_persist,
                            hipFuncAttributeMaxDynamicSharedMemorySize, smem);
  void* args[] = {(void*)&bs,  (void*)&alphas, (void*)&x,   (void*)&wtk,
                  (void*)&wtr, (void*)&hbuf,   (void*)&out, (void*)&flags};
  (void)hipLaunchCooperativeKernel((void*)lstm_persist, dim3(NWG), dim3(WGT),
                                   args, smem, stream);
}